// Round 8
// baseline (356.157 us; speedup 1.0000x reference)
//
#include <hip/hip_runtime.h>

#define N_NODES  50000
#define N_EDGES  800000
#define NTILES   3125          // 50000/16 exact
#define PT_STRIDE 3200         // partialsT row stride (floats)
#define NB1      196           // ceil(50000/256) scan blocks
// merged prep kernel block ranges
#define PBX 12500              // pack_xh: 50000*64 threads (exact)
#define PBB 25000              // pack_bits: 6.4M threads (exact)
#define PBW 40                 // Wfrag: 10240 uints (exact)
#define PBZ 196                // zero cnt
#define PB_TOT (PBX + PBB + PBW + PBZ)

typedef __attribute__((ext_vector_type(8))) short bf16x8;
typedef __attribute__((ext_vector_type(4))) float f32x4;

__device__ __forceinline__ unsigned short f2bf(float x) {
  unsigned int u = __float_as_uint(x);
  u += 0x7FFFu + ((u >> 16) & 1u);           // RNE
  return (unsigned short)(u >> 16);
}
__device__ __forceinline__ float bflo(unsigned int u) { return __uint_as_float(u << 16); }
__device__ __forceinline__ float bfhi(unsigned int u) { return __uint_as_float(u & 0xFFFF0000u); }
__device__ __forceinline__ unsigned int pack2(float a, float b) {
  return (unsigned int)f2bf(a) | ((unsigned int)f2bf(b) << 16);
}
// byte-spread popcount helpers: rep = byte B replicated 4x.
__device__ __forceinline__ unsigned int spreadLo(unsigned int rep) {
  return (((rep & 0x08040201u) + 0x7F7F7F7Fu) >> 7) & 0x01010101u;
}
__device__ __forceinline__ unsigned int spreadHi(unsigned int rep) {
  return (((rep & 0x80402010u) + 0x7F7F7F7Fu) >> 7) & 0x01010101u;
}

// ---- merged prep: X|h -> bf16, eps -> bitmask, W -> MFMA frags, zero cnt ---
// Wfrag layout (shorts): idx = kb*4096 + c*32 + q*8 + j   (32 shorts per
// (kb,c) stripe = full K=32 block; the R4/R5 bug was a 16-short stripe).
// value = bf16(W[wr(kb,q,j)][c]), wr: kb<4 -> k=kb*32+q*8+j, wr = k<96 ? k : k+32
//                                  kb=4 -> wr = 96+q*8+j  (eps rows)
__global__ void k_prep(const float* __restrict__ X, const float* __restrict__ h,
                       const float* __restrict__ eps, const float* __restrict__ W,
                       unsigned int* __restrict__ featXH, unsigned int* __restrict__ epsb,
                       unsigned int* __restrict__ Wfrag, int* __restrict__ cnt) {
  int blk = blockIdx.x, tid = threadIdx.x;
  if (blk < PBX) {
    int t = blk * 256 + tid;                 // < 3.2M exact
    int node = t >> 6, f = (t & 63) << 1;    // X/h boundary at 96 (even)
    float a, c;
    if (f < 96) { a = X[node * 96 + f];      c = X[node * 96 + f + 1]; }
    else        { a = h[node * 32 + f - 96]; c = h[node * 32 + f - 95]; }
    featXH[t] = pack2(a, c);
  } else if (blk < PBX + PBB) {
    long g = (long)(blk - PBX) * 256 + tid;  // < 6.4M exact
    float v = eps[g];
    unsigned long long m = __ballot(v > 0.5f);
    int lane = tid & 63;
    if ((lane & 31) == 0) {
      long idx = g >> 5;                     // = s*N + node
      int s = (int)(idx / N_NODES);
      int node = (int)(idx - (long)s * N_NODES);
      epsb[node * 4 + s] = (unsigned int)(m >> ((lane >> 5) * 32));
    }
  } else if (blk < PBX + PBB + PBW) {
    int u = (blk - PBX - PBB) * 256 + tid;   // < 10240 exact
    if (u < 10240) {
      int flat = u * 2;                      // even short index
      int qj = flat & 31;                    // q*8+j, 5 bits (K=32!)
      int c  = (flat >> 5) & 127;
      int kb = flat >> 12;                   // 0..4 (4 = eps block)
      int q = qj >> 3, j = qj & 7;
      int wr0;
      if (kb < 4) {
        int k = kb * 32 + q * 8 + j;
        wr0 = (k < 96) ? k : k + 32;         // h block at W rows 128..159
      } else {
        wr0 = 96 + q * 8 + j;                // eps block at W rows 96..127
      }
      Wfrag[u] = pack2(W[wr0 * 128 + c], W[(wr0 + 1) * 128 + c]);
    }
  } else {
    int i = (blk - PBX - PBB - PBW) * 256 + tid;
    if (i < N_NODES) cnt[i] = 0;
  }
}

// ---- CSR build (verbatim R7, verified) -------------------------------------
__global__ void k_hist(const int* __restrict__ dst, int* __restrict__ cnt) {
  int i = blockIdx.x * blockDim.x + threadIdx.x;
  if (i < N_EDGES) atomicAdd(&cnt[dst[i]], 1);
}

__global__ void k_scan1(const int* __restrict__ cnt, int* __restrict__ excl,
                        int* __restrict__ bsum) {
  __shared__ int wpart[4];
  int tid = threadIdx.x, lane = tid & 63, wid = tid >> 6;
  int i = blockIdx.x * 256 + tid;
  int v = (i < N_NODES) ? cnt[i] : 0;
  int x = v;
#pragma unroll
  for (int d = 1; d < 64; d <<= 1) {
    int t = __shfl_up(x, d, 64);
    if (lane >= d) x += t;
  }
  if (lane == 63) wpart[wid] = x;
  __syncthreads();
  if (tid == 0) {
    int s = 0;
#pragma unroll
    for (int w = 0; w < 4; ++w) { int t = wpart[w]; wpart[w] = s; s += t; }
    bsum[blockIdx.x] = s;
  }
  __syncthreads();
  if (i < N_NODES) excl[i] = wpart[wid] + x - v;
}

__global__ void k_scan2(const int* __restrict__ bsum, int* __restrict__ boff) {
  __shared__ int sd[256];
  int tid = threadIdx.x;
  int v = (tid < NB1) ? bsum[tid] : 0;
  sd[tid] = v;
  __syncthreads();
  for (int d = 1; d < 256; d <<= 1) {
    int t = (tid >= d) ? sd[tid - d] : 0;
    __syncthreads();
    sd[tid] += t;
    __syncthreads();
  }
  if (tid < NB1) boff[tid] = sd[tid] - v;
}

__global__ void k_scan3(int* __restrict__ off, const int* __restrict__ boff,
                        int* __restrict__ cursor) {
  int i = blockIdx.x * 256 + threadIdx.x;
  if (i < N_NODES) {
    int o = off[i] + boff[blockIdx.x];
    off[i] = o;
    cursor[i] = o;
  }
  if (i == 0) off[N_NODES] = N_EDGES;
}

__global__ void k_scatter(const int* __restrict__ src, const int* __restrict__ dst,
                          int* __restrict__ cursor, int* __restrict__ csr) {
  int i = blockIdx.x * blockDim.x + threadIdx.x;
  if (i < N_EDGES) {
    int pos = atomicAdd(&cursor[dst[i]], 1);
    csr[pos] = src[i];
  }
}

// ---- fused: aggregate 16 nodes (R7-verified core) -> LDS -> MFMA -> sum ----
// Block = tile t: nodes t*16 + (tid>>4). Lane li = tid&15 covers XH features
// 8li..8li+7 (one uint4/edge) + eps byte (li&3) of word (li>>2).
// LDS row stride 264 shorts (132 dwords ≡ 4 mod 32 banks -> ≤2-way, free).
__global__ __launch_bounds__(256) void k_fused(
    const uint4* __restrict__ feat4, const unsigned int* __restrict__ epsw,
    const unsigned short* __restrict__ Wf, const float* __restrict__ b,
    const float* __restrict__ geps_p, const int* __restrict__ off,
    const int* __restrict__ csr, float* __restrict__ partialsT) {
  __shared__ __align__(16) unsigned short lds[16 * 264];
  int tid = threadIdx.x;
  int lane = tid & 63;
  int w = tid >> 6;
  int li = tid & 15;
  int r = tid >> 4;                 // row in tile = w*4 + (lane>>4)
  int n = blockIdx.x * 16 + r;
  float ge = 1.0f + geps_p[0];
  int wsel = li >> 2, bsh = (li & 3) * 8;

  // ---- aggregation (byte-identical to R7 k_agg16) ----
  uint4 sf = feat4[n * 16 + li];
  float af0 = ge * bflo(sf.x), af1 = ge * bfhi(sf.x);
  float af2 = ge * bflo(sf.y), af3 = ge * bfhi(sf.y);
  float af4 = ge * bflo(sf.z), af5 = ge * bfhi(sf.z);
  float af6 = ge * bflo(sf.w), af7 = ge * bfhi(sf.w);
  unsigned int Bself = (epsw[n * 4 + wsel] >> bsh) & 0xFFu;
  unsigned int accLo = 0, accHi = 0;

  int e = off[n], e1 = off[n + 1];
  for (; e + 1 < e1; e += 2) {
    int s0 = csr[e], s1 = csr[e + 1];
    uint4 f0 = feat4[s0 * 16 + li];
    uint4 f1 = feat4[s1 * 16 + li];
    unsigned int w0 = epsw[s0 * 4 + wsel];
    unsigned int w1 = epsw[s1 * 4 + wsel];
    af0 += bflo(f0.x) + bflo(f1.x);  af1 += bfhi(f0.x) + bfhi(f1.x);
    af2 += bflo(f0.y) + bflo(f1.y);  af3 += bfhi(f0.y) + bfhi(f1.y);
    af4 += bflo(f0.z) + bflo(f1.z);  af5 += bfhi(f0.z) + bfhi(f1.z);
    af6 += bflo(f0.w) + bflo(f1.w);  af7 += bfhi(f0.w) + bfhi(f1.w);
    unsigned int B0 = (w0 >> bsh) & 0xFFu;
    unsigned int B1 = (w1 >> bsh) & 0xFFu;
    unsigned int r0 = B0 | (B0 << 8);  r0 |= r0 << 16;
    unsigned int r1 = B1 | (B1 << 8);  r1 |= r1 << 16;
    accLo += spreadLo(r0) + spreadLo(r1);
    accHi += spreadHi(r0) + spreadHi(r1);
  }
  if (e < e1) {
    int s0 = csr[e];
    uint4 f0 = feat4[s0 * 16 + li];
    unsigned int w0 = epsw[s0 * 4 + wsel];
    af0 += bflo(f0.x); af1 += bfhi(f0.x);
    af2 += bflo(f0.y); af3 += bfhi(f0.y);
    af4 += bflo(f0.z); af5 += bfhi(f0.z);
    af6 += bflo(f0.w); af7 += bfhi(f0.w);
    unsigned int B0 = (w0 >> bsh) & 0xFFu;
    unsigned int r0 = B0 | (B0 << 8);  r0 |= r0 << 16;
    accLo += spreadLo(r0);
    accHi += spreadHi(r0);
  }

  float ev0 = ge * (float)(Bself & 1u)        + (float)(accLo & 0xFFu);
  float ev1 = ge * (float)((Bself >> 1) & 1u) + (float)((accLo >> 8) & 0xFFu);
  float ev2 = ge * (float)((Bself >> 2) & 1u) + (float)((accLo >> 16) & 0xFFu);
  float ev3 = ge * (float)((Bself >> 3) & 1u) + (float)((accLo >> 24) & 0xFFu);
  float ev4 = ge * (float)((Bself >> 4) & 1u) + (float)(accHi & 0xFFu);
  float ev5 = ge * (float)((Bself >> 5) & 1u) + (float)((accHi >> 8) & 0xFFu);
  float ev6 = ge * (float)((Bself >> 6) & 1u) + (float)((accHi >> 16) & 0xFFu);
  float ev7 = ge * (float)((Bself >> 7) & 1u) + (float)((accHi >> 24) & 0xFFu);

  uint4 oXh, oEp;
  oXh.x = pack2(af0, af1); oXh.y = pack2(af2, af3);
  oXh.z = pack2(af4, af5); oXh.w = pack2(af6, af7);
  oEp.x = pack2(ev0, ev1); oEp.y = pack2(ev2, ev3);
  oEp.z = pack2(ev4, ev5); oEp.w = pack2(ev6, ev7);
  unsigned short* rp = lds + r * 264;
  *(uint4*)(rp + li * 8) = oXh;        // features 8li..8li+7 at short offset 8li
  *(uint4*)(rp + 128 + li * 8) = oEp;  // eps features at 128+8li
  __syncthreads();

  // ---- MFMA phase (verified epilogue; B-frags from corrected Wfrag) --------
  int col = li, quad = lane >> 4;
  bf16x8 Bsh[2][4], Bep[2];
  float bias[2];
#pragma unroll
  for (int i = 0; i < 2; ++i) {
    int c = (2 * w + i) * 16 + col;
    bias[i] = b[c];
#pragma unroll
    for (int kb = 0; kb < 4; ++kb)
      Bsh[i][kb] = *(const bf16x8*)(Wf + (kb * 128 + c) * 32 + quad * 8);
    Bep[i] = *(const bf16x8*)(Wf + (4 * 128 + c) * 32 + quad * 8);
  }

  const unsigned short* ap = lds + col * 264;
  f32x4 csh[2];
  csh[0] = (f32x4){0.f, 0.f, 0.f, 0.f};
  csh[1] = (f32x4){0.f, 0.f, 0.f, 0.f};
#pragma unroll
  for (int kb = 0; kb < 4; ++kb) {
    bf16x8 Ash = *(const bf16x8*)(ap + kb * 32 + quad * 8);
    csh[0] = __builtin_amdgcn_mfma_f32_16x16x32_bf16(Ash, Bsh[0][kb], csh[0], 0, 0, 0);
    csh[1] = __builtin_amdgcn_mfma_f32_16x16x32_bf16(Ash, Bsh[1][kb], csh[1], 0, 0, 0);
  }
#pragma unroll
  for (int s = 0; s < 4; ++s) {
    bf16x8 Aep = *(const bf16x8*)(ap + 128 + s * 32 + quad * 8);
#pragma unroll
    for (int i = 0; i < 2; ++i) {
      f32x4 c = __builtin_amdgcn_mfma_f32_16x16x32_bf16(Aep, Bep[i], csh[i], 0, 0, 0);
      float v = fmaxf(c[0] + bias[i], 0.f) + fmaxf(c[1] + bias[i], 0.f)
              + fmaxf(c[2] + bias[i], 0.f) + fmaxf(c[3] + bias[i], 0.f);
      v += __shfl_xor(v, 16, 64);
      v += __shfl_xor(v, 32, 64);
      if (quad == 0)
        partialsT[(long)(s * 128 + (2 * w + i) * 16 + col) * PT_STRIDE + blockIdx.x] = v;
    }
  }
}

// ---- reduce over tiles: one wave per output row (128 blocks = 512 waves) ---
__global__ void k_reduce(const float* __restrict__ partialsT, float* __restrict__ means) {
  int wid = (blockIdx.x * 256 + threadIdx.x) >> 6;   // 0..511
  int lane = threadIdx.x & 63;
  const float* row = partialsT + (long)wid * PT_STRIDE;
  float t = 0.f;
  for (int i = lane; i < NTILES; i += 64) t += row[i];
#pragma unroll
  for (int d = 1; d < 64; d <<= 1) t += __shfl_xor(t, d, 64);
  if (lane == 0) means[wid] = fmaxf(t * (1.0f / (float)N_NODES), 0.f);
}

// ---- broadcast output + epsilon passthrough --------------------------------
#define OUT0_F4 6400000L
#define EPS_F4  1600000L
__global__ void k_out(const float* __restrict__ means, const float* __restrict__ eps,
                      float* __restrict__ out) {
  long i = (long)blockIdx.x * blockDim.x + threadIdx.x;
  if (i < OUT0_F4) {
    int o4 = (int)(i & 31);
    long sn = i >> 5;
    int s = (int)(sn / N_NODES);
    ((float4*)out)[i] = ((const float4*)means)[s * 32 + o4];
  } else if (i < OUT0_F4 + EPS_F4) {
    long j = i - OUT0_F4;
    ((float4*)out)[OUT0_F4 + j] = ((const float4*)eps)[j];
  }
}

extern "C" void kernel_launch(void* const* d_in, const int* in_sizes, int n_in,
                              void* d_out, int out_size, void* d_ws, size_t ws_size,
                              hipStream_t stream) {
  const float* X    = (const float*)d_in[0];
  const float* h    = (const float*)d_in[1];
  const float* eps  = (const float*)d_in[2];
  const float* W    = (const float*)d_in[3];
  const float* b    = (const float*)d_in[4];
  const float* geps = (const float*)d_in[5];
  const int*   src  = (const int*)d_in[6];
  const int*   dst  = (const int*)d_in[7];
  float* out = (float*)d_out;

  char* w = (char*)d_ws;
  unsigned int* featXH = (unsigned int*)w;  w += (size_t)N_NODES * 64 * 4;   // 12.8 MB
  unsigned int* epsb   = (unsigned int*)w;  w += (size_t)N_NODES * 4 * 4;    // 0.8 MB
  unsigned int* Wfrag  = (unsigned int*)w;  w += 10240 * 4;                  // 40 KB
  int*   off      = (int*)w;   w += (size_t)(N_NODES + 16) * 4;
  int*   cnt      = (int*)w;   w += (size_t)N_NODES * 4;
  int*   cursor   = (int*)w;   w += (size_t)N_NODES * 4;
  int*   csr      = (int*)w;   w += (size_t)N_EDGES * 4;
  int*   bsum     = (int*)w;   w += 256 * 4;
  int*   boff     = (int*)w;   w += 256 * 4;
  float* partialsT = (float*)w; w += (size_t)512 * PT_STRIDE * 4;            // 6.55 MB
  float* means    = (float*)w; w += 512 * 4;

  int eb = (N_EDGES + 255) / 256;
  k_prep<<<PB_TOT, 256, 0, stream>>>(X, h, eps, W, featXH, epsb, Wfrag, cnt);
  k_hist<<<eb, 256, 0, stream>>>(dst, cnt);
  k_scan1<<<NB1, 256, 0, stream>>>(cnt, off, bsum);
  k_scan2<<<1, 256, 0, stream>>>(bsum, boff);
  k_scan3<<<NB1, 256, 0, stream>>>(off, boff, cursor);
  k_scatter<<<eb, 256, 0, stream>>>(src, dst, cursor, csr);

  k_fused<<<NTILES, 256, 0, stream>>>((const uint4*)featXH, epsb,
                                      (const unsigned short*)Wfrag, b, geps,
                                      off, csr, partialsT);
  k_reduce<<<128, 256, 0, stream>>>(partialsT, means);

  long total_f4 = OUT0_F4 + EPS_F4;
  k_out<<<(int)((total_f4 + 255) / 256), 256, 0, stream>>>(means, eps, out);
}

// Round 9
// 354.777 us; speedup vs baseline: 1.0039x; 1.0039x over previous
//
#include <hip/hip_runtime.h>

#define N_NODES  50000
#define N_EDGES  800000
#define D_OUTF   128
#define F_PACK   256          // agg row: Xh(128) | eps counts (128)
#define NTILES   3125         // 50000 / 16, exact
#define GEMM_BLOCKS 512
#define NB1      196          // ceil(50000/256) scan blocks
// merged pack kernel block ranges
#define PBX 12500             // pack_xh: 50000*64 threads (exact)
#define PBB 25000             // pack_bits: 6.4M threads (exact)
#define PBZ 196               // zero cnt
#define PB_TOT (PBX + PBB + PBZ)

typedef __attribute__((ext_vector_type(8))) short bf16x8;
typedef __attribute__((ext_vector_type(4))) float f32x4;

__device__ __forceinline__ unsigned short f2bf(float x) {
  unsigned int u = __float_as_uint(x);
  u += 0x7FFFu + ((u >> 16) & 1u);           // RNE
  return (unsigned short)(u >> 16);
}
__device__ __forceinline__ float bflo(unsigned int u) { return __uint_as_float(u << 16); }
__device__ __forceinline__ float bfhi(unsigned int u) { return __uint_as_float(u & 0xFFFF0000u); }
__device__ __forceinline__ unsigned int pack2(float a, float b) {
  return (unsigned int)f2bf(a) | ((unsigned int)f2bf(b) << 16);
}
// byte-spread popcount helpers: rep = byte B replicated 4x.
__device__ __forceinline__ unsigned int spreadLo(unsigned int rep) {
  return (((rep & 0x08040201u) + 0x7F7F7F7Fu) >> 7) & 0x01010101u;
}
__device__ __forceinline__ unsigned int spreadHi(unsigned int rep) {
  return (((rep & 0x80402010u) + 0x7F7F7F7Fu) >> 7) & 0x01010101u;
}

// ---- merged prep: pack X|h -> bf16, eps -> bitmask, zero cnt ---------------
__global__ void k_pack(const float* __restrict__ X, const float* __restrict__ h,
                       const float* __restrict__ eps,
                       unsigned int* __restrict__ featXH,
                       unsigned int* __restrict__ epsb, int* __restrict__ cnt) {
  int blk = blockIdx.x, tid = threadIdx.x;
  if (blk < PBX) {
    int t = blk * 256 + tid;                 // < 3.2M exact
    int node = t >> 6, f = (t & 63) << 1;    // X/h boundary at 96 (even)
    float a, c;
    if (f < 96) { a = X[node * 96 + f];      c = X[node * 96 + f + 1]; }
    else        { a = h[node * 32 + f - 96]; c = h[node * 32 + f - 95]; }
    featXH[t] = pack2(a, c);
  } else if (blk < PBX + PBB) {
    long g = (long)(blk - PBX) * 256 + tid;  // < 6.4M exact
    float v = eps[g];
    unsigned long long m = __ballot(v > 0.5f);
    int lane = tid & 63;
    if ((lane & 31) == 0) {
      long idx = g >> 5;                     // = s*N + node
      int s = (int)(idx / N_NODES);
      int node = (int)(idx - (long)s * N_NODES);
      epsb[node * 4 + s] = (unsigned int)(m >> ((lane >> 5) * 32));
    }
  } else {
    int i = (blk - PBX - PBB) * 256 + tid;
    if (i < N_NODES) cnt[i] = 0;
  }
}

// ---- CSR build (verbatim, verified) ----------------------------------------
__global__ void k_hist(const int* __restrict__ dst, int* __restrict__ cnt) {
  int i = blockIdx.x * blockDim.x + threadIdx.x;
  if (i < N_EDGES) atomicAdd(&cnt[dst[i]], 1);
}

__global__ void k_scan1(const int* __restrict__ cnt, int* __restrict__ excl,
                        int* __restrict__ bsum) {
  __shared__ int wpart[4];
  int tid = threadIdx.x, lane = tid & 63, wid = tid >> 6;
  int i = blockIdx.x * 256 + tid;
  int v = (i < N_NODES) ? cnt[i] : 0;
  int x = v;
#pragma unroll
  for (int d = 1; d < 64; d <<= 1) {
    int t = __shfl_up(x, d, 64);
    if (lane >= d) x += t;
  }
  if (lane == 63) wpart[wid] = x;
  __syncthreads();
  if (tid == 0) {
    int s = 0;
#pragma unroll
    for (int w = 0; w < 4; ++w) { int t = wpart[w]; wpart[w] = s; s += t; }
    bsum[blockIdx.x] = s;
  }
  __syncthreads();
  if (i < N_NODES) excl[i] = wpart[wid] + x - v;
}

__global__ void k_scan2(const int* __restrict__ bsum, int* __restrict__ boff) {
  __shared__ int sd[256];
  int tid = threadIdx.x;
  int v = (tid < NB1) ? bsum[tid] : 0;
  sd[tid] = v;
  __syncthreads();
  for (int d = 1; d < 256; d <<= 1) {
    int t = (tid >= d) ? sd[tid - d] : 0;
    __syncthreads();
    sd[tid] += t;
    __syncthreads();
  }
  if (tid < NB1) boff[tid] = sd[tid] - v;
}

__global__ void k_scan3(int* __restrict__ off, const int* __restrict__ boff,
                        int* __restrict__ cursor) {
  int i = blockIdx.x * 256 + threadIdx.x;
  if (i < N_NODES) {
    int o = off[i] + boff[blockIdx.x];
    off[i] = o;
    cursor[i] = o;
  }
  if (i == 0) off[N_NODES] = N_EDGES;
}

__global__ void k_scatter(const int* __restrict__ src, const int* __restrict__ dst,
                          int* __restrict__ cursor, int* __restrict__ csr) {
  int i = blockIdx.x * blockDim.x + threadIdx.x;
  if (i < N_EDGES) {
    int pos = atomicAdd(&cursor[dst[i]], 1);
    csr[pos] = src[i];
  }
}

// ---- aggregation: WAVE per node, 4 edge-slots x 16 feature-lanes -----------
// lane = es*16 + li: slot es walks edges off[n]+es, +es+4, ... ; lane li
// covers XH features 8li..8li+7 (uint4) + eps byte (li&3) of word (li>>2).
// Cross-slot reduce via shfl_xor(16,32); lanes 0..15 add self term and write
// the same agg layout R7's verified k_gemm consumes.
__global__ __launch_bounds__(256) void k_agg_ep(
    const uint4* __restrict__ feat4, const unsigned int* __restrict__ epsw,
    const float* __restrict__ geps_p, const int* __restrict__ off,
    const int* __restrict__ csr, uint4* __restrict__ agg4) {
  int wave = (blockIdx.x * blockDim.x + threadIdx.x) >> 6;   // node; grid exact
  int lane = threadIdx.x & 63;
  int li = lane & 15, es = lane >> 4;
  if (wave >= N_NODES) return;
  int n = wave;
  float ge = 1.0f + geps_p[0];
  int wsel = li >> 2, bsh = (li & 3) * 8;

  // prefetch self row (used after reduction by lanes 0..15)
  uint4 sf = feat4[n * 16 + li];
  unsigned int swd = epsw[n * 4 + wsel];

  float af0 = 0.f, af1 = 0.f, af2 = 0.f, af3 = 0.f;
  float af4 = 0.f, af5 = 0.f, af6 = 0.f, af7 = 0.f;
  unsigned int accLo = 0, accHi = 0;

  int e1 = off[n + 1];
  int e = off[n] + es;
  for (; e + 4 < e1; e += 8) {               // slots stride 4, unroll 2
    int s0 = csr[e], s1 = csr[e + 4];
    uint4 f0 = feat4[s0 * 16 + li];
    uint4 f1 = feat4[s1 * 16 + li];
    unsigned int w0 = epsw[s0 * 4 + wsel];
    unsigned int w1 = epsw[s1 * 4 + wsel];
    af0 += bflo(f0.x) + bflo(f1.x);  af1 += bfhi(f0.x) + bfhi(f1.x);
    af2 += bflo(f0.y) + bflo(f1.y);  af3 += bfhi(f0.y) + bfhi(f1.y);
    af4 += bflo(f0.z) + bflo(f1.z);  af5 += bfhi(f0.z) + bfhi(f1.z);
    af6 += bflo(f0.w) + bflo(f1.w);  af7 += bfhi(f0.w) + bfhi(f1.w);
    unsigned int B0 = (w0 >> bsh) & 0xFFu;
    unsigned int B1 = (w1 >> bsh) & 0xFFu;
    unsigned int r0 = B0 | (B0 << 8);  r0 |= r0 << 16;
    unsigned int r1 = B1 | (B1 << 8);  r1 |= r1 << 16;
    accLo += spreadLo(r0) + spreadLo(r1);
    accHi += spreadHi(r0) + spreadHi(r1);
  }
  if (e < e1) {
    int s0 = csr[e];
    uint4 f0 = feat4[s0 * 16 + li];
    unsigned int w0 = epsw[s0 * 4 + wsel];
    af0 += bflo(f0.x); af1 += bfhi(f0.x);
    af2 += bflo(f0.y); af3 += bfhi(f0.y);
    af4 += bflo(f0.z); af5 += bfhi(f0.z);
    af6 += bflo(f0.w); af7 += bfhi(f0.w);
    unsigned int B0 = (w0 >> bsh) & 0xFFu;
    unsigned int r0 = B0 | (B0 << 8);  r0 |= r0 << 16;
    accLo += spreadLo(r0);
    accHi += spreadHi(r0);
  }

  // cross-slot reduction (lanes differing in bits 4,5). Packed-byte adds are
  // overflow-safe: per-byte totals <= degree << 255.
#pragma unroll
  for (int d = 16; d < 64; d <<= 1) {
    af0 += __shfl_xor(af0, d, 64);  af1 += __shfl_xor(af1, d, 64);
    af2 += __shfl_xor(af2, d, 64);  af3 += __shfl_xor(af3, d, 64);
    af4 += __shfl_xor(af4, d, 64);  af5 += __shfl_xor(af5, d, 64);
    af6 += __shfl_xor(af6, d, 64);  af7 += __shfl_xor(af7, d, 64);
    accLo += __shfl_xor((int)accLo, d, 64);
    accHi += __shfl_xor((int)accHi, d, 64);
  }

  if (es == 0) {
    // self term
    af0 += ge * bflo(sf.x);  af1 += ge * bfhi(sf.x);
    af2 += ge * bflo(sf.y);  af3 += ge * bfhi(sf.y);
    af4 += ge * bflo(sf.z);  af5 += ge * bfhi(sf.z);
    af6 += ge * bflo(sf.w);  af7 += ge * bfhi(sf.w);
    unsigned int Bself = (swd >> bsh) & 0xFFu;
    float ev0 = ge * (float)(Bself & 1u)        + (float)(accLo & 0xFFu);
    float ev1 = ge * (float)((Bself >> 1) & 1u) + (float)((accLo >> 8) & 0xFFu);
    float ev2 = ge * (float)((Bself >> 2) & 1u) + (float)((accLo >> 16) & 0xFFu);
    float ev3 = ge * (float)((Bself >> 3) & 1u) + (float)((accLo >> 24) & 0xFFu);
    float ev4 = ge * (float)((Bself >> 4) & 1u) + (float)(accHi & 0xFFu);
    float ev5 = ge * (float)((Bself >> 5) & 1u) + (float)((accHi >> 8) & 0xFFu);
    float ev6 = ge * (float)((Bself >> 6) & 1u) + (float)((accHi >> 16) & 0xFFu);
    float ev7 = ge * (float)((Bself >> 7) & 1u) + (float)((accHi >> 24) & 0xFFu);

    uint4 oXh, oEp;
    oXh.x = pack2(af0, af1); oXh.y = pack2(af2, af3);
    oXh.z = pack2(af4, af5); oXh.w = pack2(af6, af7);
    oEp.x = pack2(ev0, ev1); oEp.y = pack2(ev2, ev3);
    oEp.z = pack2(ev4, ev5); oEp.w = pack2(ev6, ev7);
    agg4[n * 32 + li]      = oXh;   // features 8li..8li+7
    agg4[n * 32 + 16 + li] = oEp;   // eps features 128+8li..+7
  }
}

// ---- MFMA GEMM + bias + ReLU + node-sum (VERBATIM R3/R6/R7, verified) ------
__global__ __launch_bounds__(256) void k_gemm(const unsigned short* __restrict__ agg,
    const float* __restrict__ W, const float* __restrict__ b,
    float* __restrict__ partials) {
  int tid = threadIdx.x;
  int lane = tid & 63;
  int w = tid >> 6;          // wave -> n-tiles {2w, 2w+1}
  int col = lane & 15;
  int quad = lane >> 4;

  bf16x8 Bsh[2][4];
  bf16x8 Bep[2];
  float bias[2];
#pragma unroll
  for (int i = 0; i < 2; ++i) {
    int obase = (2 * w + i) * 16;
    bias[i] = b[obase + col];
#pragma unroll
    for (int kb = 0; kb < 4; ++kb) {
      bf16x8 f;
#pragma unroll
      for (int j = 0; j < 8; ++j) {
        int k = kb * 32 + quad * 8 + j;
        int wr = (k < 96) ? k : k + 32;            // h block at W rows 128..159
        f[j] = (short)f2bf(W[wr * D_OUTF + obase + col]);
      }
      Bsh[i][kb] = f;
    }
    bf16x8 g;
#pragma unroll
    for (int j = 0; j < 8; ++j)
      g[j] = (short)f2bf(W[(96 + quad * 8 + j) * D_OUTF + obase + col]);
    Bep[i] = g;
  }

  f32x4 psum[4][2];
#pragma unroll
  for (int s = 0; s < 4; ++s)
#pragma unroll
    for (int i = 0; i < 2; ++i) psum[s][i] = (f32x4){0.f, 0.f, 0.f, 0.f};

  for (int t = blockIdx.x; t < NTILES; t += gridDim.x) {
    const unsigned short* arow = agg + (long)(t * 16 + col) * F_PACK;
    bf16x8 Ash[4];
#pragma unroll
    for (int kb = 0; kb < 4; ++kb)
      Ash[kb] = *(const bf16x8*)(arow + kb * 32 + quad * 8);
    f32x4 csh[2];
    csh[0] = (f32x4){0.f, 0.f, 0.f, 0.f};
    csh[1] = (f32x4){0.f, 0.f, 0.f, 0.f};
#pragma unroll
    for (int kb = 0; kb < 4; ++kb) {
      csh[0] = __builtin_amdgcn_mfma_f32_16x16x32_bf16(Ash[kb], Bsh[0][kb], csh[0], 0, 0, 0);
      csh[1] = __builtin_amdgcn_mfma_f32_16x16x32_bf16(Ash[kb], Bsh[1][kb], csh[1], 0, 0, 0);
    }
#pragma unroll
    for (int s = 0; s < 4; ++s) {
      bf16x8 Aep = *(const bf16x8*)(arow + 128 + s * 32 + quad * 8);
#pragma unroll
      for (int i = 0; i < 2; ++i) {
        f32x4 c = __builtin_amdgcn_mfma_f32_16x16x32_bf16(Aep, Bep[i], csh[i], 0, 0, 0);
#pragma unroll
        for (int r = 0; r < 4; ++r)
          psum[s][i][r] += fmaxf(c[r] + bias[i], 0.f);
      }
    }
  }

#pragma unroll
  for (int s = 0; s < 4; ++s)
#pragma unroll
    for (int i = 0; i < 2; ++i) {
      float v = psum[s][i][0] + psum[s][i][1] + psum[s][i][2] + psum[s][i][3];
      v += __shfl_xor(v, 16, 64);
      v += __shfl_xor(v, 32, 64);
      if (quad == 0)
        partials[blockIdx.x * 512 + s * 128 + (2 * w + i) * 16 + col] = v;
    }
}

__global__ void k_reduce(const float* __restrict__ partials, float* __restrict__ means) {
  int idx = blockIdx.x * 64 + threadIdx.x;   // 8 x 64 -> 512
  float t = 0.f;
  for (int blk = 0; blk < GEMM_BLOCKS; ++blk) t += partials[blk * 512 + idx];
  means[idx] = fmaxf(t * (1.0f / (float)N_NODES), 0.f);
}

// ---- broadcast output + epsilon passthrough --------------------------------
#define OUT0_F4 6400000L
#define EPS_F4  1600000L
__global__ void k_out(const float* __restrict__ means, const float* __restrict__ eps,
                      float* __restrict__ out) {
  long i = (long)blockIdx.x * blockDim.x + threadIdx.x;
  if (i < OUT0_F4) {
    int o4 = (int)(i & 31);
    long sn = i >> 5;
    int s = (int)(sn / N_NODES);
    ((float4*)out)[i] = ((const float4*)means)[s * 32 + o4];
  } else if (i < OUT0_F4 + EPS_F4) {
    long j = i - OUT0_F4;
    ((float4*)out)[OUT0_F4 + j] = ((const float4*)eps)[j];
  }
}

extern "C" void kernel_launch(void* const* d_in, const int* in_sizes, int n_in,
                              void* d_out, int out_size, void* d_ws, size_t ws_size,
                              hipStream_t stream) {
  const float* X    = (const float*)d_in[0];
  const float* h    = (const float*)d_in[1];
  const float* eps  = (const float*)d_in[2];
  const float* W    = (const float*)d_in[3];
  const float* b    = (const float*)d_in[4];
  const float* geps = (const float*)d_in[5];
  const int*   src  = (const int*)d_in[6];
  const int*   dst  = (const int*)d_in[7];
  float* out = (float*)d_out;

  char* w = (char*)d_ws;
  unsigned int*  featXH = (unsigned int*)w;  w += (size_t)N_NODES * 64 * 4;   // 12.8 MB
  unsigned int*  epsb   = (unsigned int*)w;  w += (size_t)N_NODES * 4 * 4;    // 0.8 MB
  unsigned int*  agg_u  = (unsigned int*)w;  w += (size_t)N_NODES * 128 * 4;  // 25.6 MB
  int*   off      = (int*)w;   w += (size_t)(N_NODES + 16) * 4;
  int*   cnt      = (int*)w;   w += (size_t)N_NODES * 4;
  int*   cursor   = (int*)w;   w += (size_t)N_NODES * 4;
  int*   csr      = (int*)w;   w += (size_t)N_EDGES * 4;
  int*   bsum     = (int*)w;   w += 256 * 4;
  int*   boff     = (int*)w;   w += 256 * 4;
  float* partials = (float*)w; w += (size_t)GEMM_BLOCKS * 512 * 4;
  float* means    = (float*)w; w += 512 * 4;

  int eb = (N_EDGES + 255) / 256;
  k_pack<<<PB_TOT, 256, 0, stream>>>(X, h, eps, featXH, epsb, cnt);
  k_hist<<<eb, 256, 0, stream>>>(dst, cnt);
  k_scan1<<<NB1, 256, 0, stream>>>(cnt, off, bsum);
  k_scan2<<<1, 256, 0, stream>>>(bsum, boff);
  k_scan3<<<NB1, 256, 0, stream>>>(off, boff, cursor);
  k_scatter<<<eb, 256, 0, stream>>>(src, dst, cursor, csr);

  k_agg_ep<<<(N_NODES * 64) / 256, 256, 0, stream>>>((const uint4*)featXH, epsb,
                                                     geps, off, csr, (uint4*)agg_u);

  k_gemm<<<GEMM_BLOCKS, 256, 0, stream>>>((const unsigned short*)agg_u, W, b, partials);
  k_reduce<<<8, 64, 0, stream>>>(partials, means);

  long total_f4 = OUT0_F4 + EPS_F4;
  k_out<<<(int)((total_f4 + 255) / 256), 256, 0, stream>>>(means, eps, out);
}

// Round 10
// 341.687 us; speedup vs baseline: 1.0423x; 1.0383x over previous
//
#include <hip/hip_runtime.h>

#define N_NODES  50000
#define N_EDGES  800000
#define D_OUTF   128
#define F_PACK   256          // agg row: Xh(128) | eps counts (128), bf16
#define NTILES   3125         // 50000 / 16, exact
#define GEMM_BLOCKS 512
#define NB1      196          // ceil(50000/256) scan blocks
// merged pack kernel block ranges
#define PBX 6250              // pack_xh fp8: 50000*32 threads (exact)
#define PBB 25000             // pack_bits: 6.4M threads (exact)
#define PBZ 196               // zero cnt
#define PB_TOT (PBX + PBB + PBZ)

typedef __attribute__((ext_vector_type(8))) short bf16x8;
typedef __attribute__((ext_vector_type(4))) float f32x4;
typedef __attribute__((ext_vector_type(2))) float f32x2;

__device__ __forceinline__ unsigned short f2bf(float x) {
  unsigned int u = __float_as_uint(x);
  u += 0x7FFFu + ((u >> 16) & 1u);           // RNE
  return (unsigned short)(u >> 16);
}
__device__ __forceinline__ float bflo(unsigned int u) { return __uint_as_float(u << 16); }
__device__ __forceinline__ float bfhi(unsigned int u) { return __uint_as_float(u & 0xFFFF0000u); }
__device__ __forceinline__ unsigned int pack2(float a, float b) {
  return (unsigned int)f2bf(a) | ((unsigned int)f2bf(b) << 16);
}
// byte-spread popcount helpers: rep = byte B replicated 4x.
__device__ __forceinline__ unsigned int spreadLo(unsigned int rep) {
  return (((rep & 0x08040201u) + 0x7F7F7F7Fu) >> 7) & 0x01010101u;
}
__device__ __forceinline__ unsigned int spreadHi(unsigned int rep) {
  return (((rep & 0x80402010u) + 0x7F7F7F7Fu) >> 7) & 0x01010101u;
}
// accumulate 4 fp8 (one dword) into 4 fp32 accumulators
__device__ __forceinline__ void f8acc(unsigned int w, float& a0, float& a1,
                                      float& a2, float& a3) {
  f32x2 p0 = __builtin_amdgcn_cvt_pk_f32_fp8(w, false);  // bytes 0,1
  f32x2 p1 = __builtin_amdgcn_cvt_pk_f32_fp8(w, true);   // bytes 2,3
  a0 += p0.x; a1 += p0.y; a2 += p1.x; a3 += p1.y;
}

// ---- merged prep: pack X|h -> fp8 e4m3, eps -> bitmask, zero cnt -----------
__global__ void k_pack(const float* __restrict__ X, const float* __restrict__ h,
                       const float* __restrict__ eps,
                       unsigned int* __restrict__ featF8,
                       unsigned int* __restrict__ epsb, int* __restrict__ cnt) {
  int blk = blockIdx.x, tid = threadIdx.x;
  if (blk < PBX) {
    int t = blk * 256 + tid;                 // < 1.6M exact (node, feature-quad)
    int node = t >> 5, f = (t & 31) << 2;    // X/h boundary at 96 (mult of 4)
    float a0, a1, a2, a3;
    if (f < 96) {
      const float* p = X + node * 96 + f;
      a0 = p[0]; a1 = p[1]; a2 = p[2]; a3 = p[3];
    } else {
      const float* p = h + node * 32 + (f - 96);
      a0 = p[0]; a1 = p[1]; a2 = p[2]; a3 = p[3];
    }
    unsigned int d = __builtin_amdgcn_cvt_pk_fp8_f32(a0, a1, 0, false);
    d = __builtin_amdgcn_cvt_pk_fp8_f32(a2, a3, d, true);
    featF8[t] = d;                           // feature f' at byte f'%4 of dword f'/4
  } else if (blk < PBX + PBB) {
    long g = (long)(blk - PBX) * 256 + tid;  // < 6.4M exact
    float v = eps[g];
    unsigned long long m = __ballot(v > 0.5f);
    int lane = tid & 63;
    if ((lane & 31) == 0) {
      long idx = g >> 5;                     // = s*N + node
      int s = (int)(idx / N_NODES);
      int node = (int)(idx - (long)s * N_NODES);
      epsb[node * 4 + s] = (unsigned int)(m >> ((lane >> 5) * 32));
    }
  } else {
    int i = (blk - PBX - PBB) * 256 + tid;
    if (i < N_NODES) cnt[i] = 0;
  }
}

// ---- CSR build (verbatim, verified) ----------------------------------------
__global__ void k_hist(const int* __restrict__ dst, int* __restrict__ cnt) {
  int i = blockIdx.x * blockDim.x + threadIdx.x;
  if (i < N_EDGES) atomicAdd(&cnt[dst[i]], 1);
}

__global__ void k_scan1(const int* __restrict__ cnt, int* __restrict__ excl,
                        int* __restrict__ bsum) {
  __shared__ int wpart[4];
  int tid = threadIdx.x, lane = tid & 63, wid = tid >> 6;
  int i = blockIdx.x * 256 + tid;
  int v = (i < N_NODES) ? cnt[i] : 0;
  int x = v;
#pragma unroll
  for (int d = 1; d < 64; d <<= 1) {
    int t = __shfl_up(x, d, 64);
    if (lane >= d) x += t;
  }
  if (lane == 63) wpart[wid] = x;
  __syncthreads();
  if (tid == 0) {
    int s = 0;
#pragma unroll
    for (int w = 0; w < 4; ++w) { int t = wpart[w]; wpart[w] = s; s += t; }
    bsum[blockIdx.x] = s;
  }
  __syncthreads();
  if (i < N_NODES) excl[i] = wpart[wid] + x - v;
}

__global__ void k_scan2(const int* __restrict__ bsum, int* __restrict__ boff) {
  __shared__ int sd[256];
  int tid = threadIdx.x;
  int v = (tid < NB1) ? bsum[tid] : 0;
  sd[tid] = v;
  __syncthreads();
  for (int d = 1; d < 256; d <<= 1) {
    int t = (tid >= d) ? sd[tid - d] : 0;
    __syncthreads();
    sd[tid] += t;
    __syncthreads();
  }
  if (tid < NB1) boff[tid] = sd[tid] - v;
}

__global__ void k_scan3(int* __restrict__ off, const int* __restrict__ boff,
                        int* __restrict__ cursor) {
  int i = blockIdx.x * 256 + threadIdx.x;
  if (i < N_NODES) {
    int o = off[i] + boff[blockIdx.x];
    off[i] = o;
    cursor[i] = o;
  }
  if (i == 0) off[N_NODES] = N_EDGES;
}

__global__ void k_scatter(const int* __restrict__ src, const int* __restrict__ dst,
                          int* __restrict__ cursor, int* __restrict__ csr) {
  int i = blockIdx.x * blockDim.x + threadIdx.x;
  if (i < N_EDGES) {
    int pos = atomicAdd(&cursor[dst[i]], 1);
    csr[pos] = src[i];
  }
}

// ---- aggregation: WAVE per node, 4 edge-slots x 16 feature-lanes, fp8 ------
// lane = es*16 + li: slot es walks edges off[n]+es, +es+4, ... ; lane li
// covers XH features 8li..8li+7 (uint2, 8 B fp8) + eps byte (li&3) of word
// (li>>2). Cross-slot reduce via shfl_xor(16,32); lanes 0..15 add the self
// term and write the same bf16 agg layout the verified k_gemm consumes.
__global__ __launch_bounds__(256) void k_agg_ep(
    const uint2* __restrict__ feat2, const unsigned int* __restrict__ epsw,
    const float* __restrict__ geps_p, const int* __restrict__ off,
    const int* __restrict__ csr, uint4* __restrict__ agg4) {
  int wave = (blockIdx.x * blockDim.x + threadIdx.x) >> 6;   // node; grid exact
  int lane = threadIdx.x & 63;
  int li = lane & 15, es = lane >> 4;
  if (wave >= N_NODES) return;
  int n = wave;
  float ge = 1.0f + geps_p[0];
  int wsel = li >> 2, bsh = (li & 3) * 8;

  // prefetch self row (used after reduction by lanes 0..15)
  uint2 sf = feat2[n * 16 + li];
  unsigned int swd = epsw[n * 4 + wsel];

  float af0 = 0.f, af1 = 0.f, af2 = 0.f, af3 = 0.f;
  float af4 = 0.f, af5 = 0.f, af6 = 0.f, af7 = 0.f;
  unsigned int accLo = 0, accHi = 0;

  int e1 = off[n + 1];
  int e = off[n] + es;
  for (; e + 4 < e1; e += 8) {               // slots stride 4, unroll 2
    int s0 = csr[e], s1 = csr[e + 4];
    uint2 f0 = feat2[s0 * 16 + li];
    uint2 f1 = feat2[s1 * 16 + li];
    unsigned int w0 = epsw[s0 * 4 + wsel];
    unsigned int w1 = epsw[s1 * 4 + wsel];
    f8acc(f0.x, af0, af1, af2, af3);  f8acc(f0.y, af4, af5, af6, af7);
    f8acc(f1.x, af0, af1, af2, af3);  f8acc(f1.y, af4, af5, af6, af7);
    unsigned int B0 = (w0 >> bsh) & 0xFFu;
    unsigned int B1 = (w1 >> bsh) & 0xFFu;
    unsigned int r0 = B0 | (B0 << 8);  r0 |= r0 << 16;
    unsigned int r1 = B1 | (B1 << 8);  r1 |= r1 << 16;
    accLo += spreadLo(r0) + spreadLo(r1);
    accHi += spreadHi(r0) + spreadHi(r1);
  }
  if (e < e1) {
    int s0 = csr[e];
    uint2 f0 = feat2[s0 * 16 + li];
    unsigned int w0 = epsw[s0 * 4 + wsel];
    f8acc(f0.x, af0, af1, af2, af3);  f8acc(f0.y, af4, af5, af6, af7);
    unsigned int B0 = (w0 >> bsh) & 0xFFu;
    unsigned int r0 = B0 | (B0 << 8);  r0 |= r0 << 16;
    accLo += spreadLo(r0);
    accHi += spreadHi(r0);
  }

  // cross-slot reduction (lanes differing in bits 4,5). Packed-byte adds are
  // overflow-safe: per-byte totals <= degree << 255.
#pragma unroll
  for (int d = 16; d < 64; d <<= 1) {
    af0 += __shfl_xor(af0, d, 64);  af1 += __shfl_xor(af1, d, 64);
    af2 += __shfl_xor(af2, d, 64);  af3 += __shfl_xor(af3, d, 64);
    af4 += __shfl_xor(af4, d, 64);  af5 += __shfl_xor(af5, d, 64);
    af6 += __shfl_xor(af6, d, 64);  af7 += __shfl_xor(af7, d, 64);
    accLo += __shfl_xor((int)accLo, d, 64);
    accHi += __shfl_xor((int)accHi, d, 64);
  }

  if (es == 0) {
    // self term (fp8-rounded features, weight ge)
    f32x2 s0 = __builtin_amdgcn_cvt_pk_f32_fp8(sf.x, false);
    f32x2 s1 = __builtin_amdgcn_cvt_pk_f32_fp8(sf.x, true);
    f32x2 s2 = __builtin_amdgcn_cvt_pk_f32_fp8(sf.y, false);
    f32x2 s3 = __builtin_amdgcn_cvt_pk_f32_fp8(sf.y, true);
    af0 += ge * s0.x;  af1 += ge * s0.y;
    af2 += ge * s1.x;  af3 += ge * s1.y;
    af4 += ge * s2.x;  af5 += ge * s2.y;
    af6 += ge * s3.x;  af7 += ge * s3.y;
    unsigned int Bself = (swd >> bsh) & 0xFFu;
    float ev0 = ge * (float)(Bself & 1u)        + (float)(accLo & 0xFFu);
    float ev1 = ge * (float)((Bself >> 1) & 1u) + (float)((accLo >> 8) & 0xFFu);
    float ev2 = ge * (float)((Bself >> 2) & 1u) + (float)((accLo >> 16) & 0xFFu);
    float ev3 = ge * (float)((Bself >> 3) & 1u) + (float)((accLo >> 24) & 0xFFu);
    float ev4 = ge * (float)((Bself >> 4) & 1u) + (float)(accHi & 0xFFu);
    float ev5 = ge * (float)((Bself >> 5) & 1u) + (float)((accHi >> 8) & 0xFFu);
    float ev6 = ge * (float)((Bself >> 6) & 1u) + (float)((accHi >> 16) & 0xFFu);
    float ev7 = ge * (float)((Bself >> 7) & 1u) + (float)((accHi >> 24) & 0xFFu);

    uint4 oXh, oEp;
    oXh.x = pack2(af0, af1); oXh.y = pack2(af2, af3);
    oXh.z = pack2(af4, af5); oXh.w = pack2(af6, af7);
    oEp.x = pack2(ev0, ev1); oEp.y = pack2(ev2, ev3);
    oEp.z = pack2(ev4, ev5); oEp.w = pack2(ev6, ev7);
    agg4[n * 32 + li]      = oXh;   // features 8li..8li+7
    agg4[n * 32 + 16 + li] = oEp;   // eps features 128+8li..+7
  }
}

// ---- MFMA GEMM + bias + ReLU + node-sum (VERBATIM, verified) ---------------
__global__ __launch_bounds__(256) void k_gemm(const unsigned short* __restrict__ agg,
    const float* __restrict__ W, const float* __restrict__ b,
    float* __restrict__ partials) {
  int tid = threadIdx.x;
  int lane = tid & 63;
  int w = tid >> 6;          // wave -> n-tiles {2w, 2w+1}
  int col = lane & 15;
  int quad = lane >> 4;

  bf16x8 Bsh[2][4];
  bf16x8 Bep[2];
  float bias[2];
#pragma unroll
  for (int i = 0; i < 2; ++i) {
    int obase = (2 * w + i) * 16;
    bias[i] = b[obase + col];
#pragma unroll
    for (int kb = 0; kb < 4; ++kb) {
      bf16x8 f;
#pragma unroll
      for (int j = 0; j < 8; ++j) {
        int k = kb * 32 + quad * 8 + j;
        int wr = (k < 96) ? k : k + 32;            // h block at W rows 128..159
        f[j] = (short)f2bf(W[wr * D_OUTF + obase + col]);
      }
      Bsh[i][kb] = f;
    }
    bf16x8 g;
#pragma unroll
    for (int j = 0; j < 8; ++j)
      g[j] = (short)f2bf(W[(96 + quad * 8 + j) * D_OUTF + obase + col]);
    Bep[i] = g;
  }

  f32x4 psum[4][2];
#pragma unroll
  for (int s = 0; s < 4; ++s)
#pragma unroll
    for (int i = 0; i < 2; ++i) psum[s][i] = (f32x4){0.f, 0.f, 0.f, 0.f};

  for (int t = blockIdx.x; t < NTILES; t += gridDim.x) {
    const unsigned short* arow = agg + (long)(t * 16 + col) * F_PACK;
    bf16x8 Ash[4];
#pragma unroll
    for (int kb = 0; kb < 4; ++kb)
      Ash[kb] = *(const bf16x8*)(arow + kb * 32 + quad * 8);
    f32x4 csh[2];
    csh[0] = (f32x4){0.f, 0.f, 0.f, 0.f};
    csh[1] = (f32x4){0.f, 0.f, 0.f, 0.f};
#pragma unroll
    for (int kb = 0; kb < 4; ++kb) {
      csh[0] = __builtin_amdgcn_mfma_f32_16x16x32_bf16(Ash[kb], Bsh[0][kb], csh[0], 0, 0, 0);
      csh[1] = __builtin_amdgcn_mfma_f32_16x16x32_bf16(Ash[kb], Bsh[1][kb], csh[1], 0, 0, 0);
    }
#pragma unroll
    for (int s = 0; s < 4; ++s) {
      bf16x8 Aep = *(const bf16x8*)(arow + 128 + s * 32 + quad * 8);
#pragma unroll
      for (int i = 0; i < 2; ++i) {
        f32x4 c = __builtin_amdgcn_mfma_f32_16x16x32_bf16(Aep, Bep[i], csh[i], 0, 0, 0);
#pragma unroll
        for (int r = 0; r < 4; ++r)
          psum[s][i][r] += fmaxf(c[r] + bias[i], 0.f);
      }
    }
  }

#pragma unroll
  for (int s = 0; s < 4; ++s)
#pragma unroll
    for (int i = 0; i < 2; ++i) {
      float v = psum[s][i][0] + psum[s][i][1] + psum[s][i][2] + psum[s][i][3];
      v += __shfl_xor(v, 16, 64);
      v += __shfl_xor(v, 32, 64);
      if (quad == 0)
        partials[blockIdx.x * 512 + s * 128 + (2 * w + i) * 16 + col] = v;
    }
}

__global__ void k_reduce(const float* __restrict__ partials, float* __restrict__ means) {
  int idx = blockIdx.x * 64 + threadIdx.x;   // 8 x 64 -> 512
  float t = 0.f;
  for (int blk = 0; blk < GEMM_BLOCKS; ++blk) t += partials[blk * 512 + idx];
  means[idx] = fmaxf(t * (1.0f / (float)N_NODES), 0.f);
}

// ---- broadcast output + epsilon passthrough --------------------------------
#define OUT0_F4 6400000L
#define EPS_F4  1600000L
__global__ void k_out(const float* __restrict__ means, const float* __restrict__ eps,
                      float* __restrict__ out) {
  long i = (long)blockIdx.x * blockDim.x + threadIdx.x;
  if (i < OUT0_F4) {
    int o4 = (int)(i & 31);
    long sn = i >> 5;
    int s = (int)(sn / N_NODES);
    ((float4*)out)[i] = ((const float4*)means)[s * 32 + o4];
  } else if (i < OUT0_F4 + EPS_F4) {
    long j = i - OUT0_F4;
    ((float4*)out)[OUT0_F4 + j] = ((const float4*)eps)[j];
  }
}

extern "C" void kernel_launch(void* const* d_in, const int* in_sizes, int n_in,
                              void* d_out, int out_size, void* d_ws, size_t ws_size,
                              hipStream_t stream) {
  const float* X    = (const float*)d_in[0];
  const float* h    = (const float*)d_in[1];
  const float* eps  = (const float*)d_in[2];
  const float* W    = (const float*)d_in[3];
  const float* b    = (const float*)d_in[4];
  const float* geps = (const float*)d_in[5];
  const int*   src  = (const int*)d_in[6];
  const int*   dst  = (const int*)d_in[7];
  float* out = (float*)d_out;

  char* w = (char*)d_ws;
  unsigned int*  featF8 = (unsigned int*)w;  w += (size_t)N_NODES * 32 * 4;   // 6.4 MB
  unsigned int*  epsb   = (unsigned int*)w;  w += (size_t)N_NODES * 4 * 4;    // 0.8 MB
  unsigned int*  agg_u  = (unsigned int*)w;  w += (size_t)N_NODES * 128 * 4;  // 25.6 MB
  int*   off      = (int*)w;   w += (size_t)(N_NODES + 16) * 4;
  int*   cnt      = (int*)w;   w += (size_t)N_NODES * 4;
  int*   cursor   = (int*)w;   w += (size_t)N_NODES * 4;
  int*   csr      = (int*)w;   w += (size_t)N_EDGES * 4;
  int*   bsum     = (int*)w;   w += 256 * 4;
  int*   boff     = (int*)w;   w += 256 * 4;
  float* partials = (float*)w; w += (size_t)GEMM_BLOCKS * 512 * 4;
  float* means    = (float*)w; w += 512 * 4;

  int eb = (N_EDGES + 255) / 256;
  k_pack<<<PB_TOT, 256, 0, stream>>>(X, h, eps, featF8, epsb, cnt);
  k_hist<<<eb, 256, 0, stream>>>(dst, cnt);
  k_scan1<<<NB1, 256, 0, stream>>>(cnt, off, bsum);
  k_scan2<<<1, 256, 0, stream>>>(bsum, boff);
  k_scan3<<<NB1, 256, 0, stream>>>(off, boff, cursor);
  k_scatter<<<eb, 256, 0, stream>>>(src, dst, cursor, csr);

  k_agg_ep<<<(N_NODES * 64) / 256, 256, 0, stream>>>((const uint2*)featF8, epsb,
                                                     geps, off, csr, (uint4*)agg_u);

  k_gemm<<<GEMM_BLOCKS, 256, 0, stream>>>((const unsigned short*)agg_u, W, b, partials);
  k_reduce<<<8, 64, 0, stream>>>(partials, means);

  long total_f4 = OUT0_F4 + EPS_F4;
  k_out<<<(int)((total_f4 + 255) / 256), 256, 0, stream>>>(means, eps, out);
}

// Round 11
// 333.390 us; speedup vs baseline: 1.0683x; 1.0249x over previous
//
#include <hip/hip_runtime.h>

#define N_NODES  50000
#define N_EDGES  800000
#define D_OUTF   128
#define F_PACK   256          // agg row: Xh(128) | eps counts (128), bf16
#define NTILES   3125         // 50000 / 16, exact
#define GEMM_BLOCKS 512
#define NB1      196          // ceil(50000/256) scan blocks
// merged pack kernel block ranges
#define PBX 6250              // pack_xh fp8: 50000*32 threads (exact)
#define PBB 25000             // pack_bits: 6.4M threads (exact)
#define PBZ 196               // zero cnt
#define PB_TOT (PBX + PBB + PBZ + 1)   // +1 block zeroes sums[512]

typedef __attribute__((ext_vector_type(8))) short bf16x8;
typedef __attribute__((ext_vector_type(4))) float f32x4;
typedef __attribute__((ext_vector_type(2))) float f32x2;

__device__ __forceinline__ unsigned short f2bf(float x) {
  unsigned int u = __float_as_uint(x);
  u += 0x7FFFu + ((u >> 16) & 1u);           // RNE
  return (unsigned short)(u >> 16);
}
__device__ __forceinline__ float bflo(unsigned int u) { return __uint_as_float(u << 16); }
__device__ __forceinline__ float bfhi(unsigned int u) { return __uint_as_float(u & 0xFFFF0000u); }
__device__ __forceinline__ unsigned int pack2(float a, float b) {
  return (unsigned int)f2bf(a) | ((unsigned int)f2bf(b) << 16);
}
// byte-spread popcount helpers: rep = byte B replicated 4x.
__device__ __forceinline__ unsigned int spreadLo(unsigned int rep) {
  return (((rep & 0x08040201u) + 0x7F7F7F7Fu) >> 7) & 0x01010101u;
}
__device__ __forceinline__ unsigned int spreadHi(unsigned int rep) {
  return (((rep & 0x80402010u) + 0x7F7F7F7Fu) >> 7) & 0x01010101u;
}
// accumulate 4 fp8 (one dword) into 4 fp32 accumulators
__device__ __forceinline__ void f8acc(unsigned int w, float& a0, float& a1,
                                      float& a2, float& a3) {
  f32x2 p0 = __builtin_amdgcn_cvt_pk_f32_fp8(w, false);  // bytes 0,1
  f32x2 p1 = __builtin_amdgcn_cvt_pk_f32_fp8(w, true);   // bytes 2,3
  a0 += p0.x; a1 += p0.y; a2 += p1.x; a3 += p1.y;
}

// ---- merged prep: X|h -> fp8 e4m3, eps -> bitmask, zero cnt & sums ---------
__global__ void k_pack(const float* __restrict__ X, const float* __restrict__ h,
                       const float* __restrict__ eps,
                       unsigned int* __restrict__ featF8,
                       unsigned int* __restrict__ epsb, int* __restrict__ cnt,
                       float* __restrict__ sums) {
  int blk = blockIdx.x, tid = threadIdx.x;
  if (blk < PBX) {
    int t = blk * 256 + tid;                 // < 1.6M exact (node, feature-quad)
    int node = t >> 5, f = (t & 31) << 2;    // X/h boundary at 96 (mult of 4)
    float a0, a1, a2, a3;
    if (f < 96) {
      const float* p = X + node * 96 + f;
      a0 = p[0]; a1 = p[1]; a2 = p[2]; a3 = p[3];
    } else {
      const float* p = h + node * 32 + (f - 96);
      a0 = p[0]; a1 = p[1]; a2 = p[2]; a3 = p[3];
    }
    unsigned int d = __builtin_amdgcn_cvt_pk_fp8_f32(a0, a1, 0, false);
    d = __builtin_amdgcn_cvt_pk_fp8_f32(a2, a3, d, true);
    featF8[t] = d;                           // feature f' at byte f'%4 of dword f'/4
  } else if (blk < PBX + PBB) {
    long g = (long)(blk - PBX) * 256 + tid;  // < 6.4M exact
    float v = eps[g];
    unsigned long long m = __ballot(v > 0.5f);
    int lane = tid & 63;
    if ((lane & 31) == 0) {
      long idx = g >> 5;                     // = s*N + node
      int s = (int)(idx / N_NODES);
      int node = (int)(idx - (long)s * N_NODES);
      epsb[node * 4 + s] = (unsigned int)(m >> ((lane >> 5) * 32));
    }
  } else if (blk < PBX + PBB + PBZ) {
    int i = (blk - PBX - PBB) * 256 + tid;
    if (i < N_NODES) cnt[i] = 0;
  } else {
    sums[tid] = 0.f;
    sums[tid + 256] = 0.f;
  }
}

// ---- CSR build -------------------------------------------------------------
__global__ void k_hist(const int* __restrict__ dst, int* __restrict__ cnt) {
  int i = blockIdx.x * blockDim.x + threadIdx.x;
  if (i < N_EDGES) atomicAdd(&cnt[dst[i]], 1);
}

// scan1: excl[i] = block-LOCAL exclusive prefix; bsum[blk] = block total.
__global__ void k_scan1(const int* __restrict__ cnt, int* __restrict__ excl,
                        int* __restrict__ bsum) {
  __shared__ int wpart[4];
  int tid = threadIdx.x, lane = tid & 63, wid = tid >> 6;
  int i = blockIdx.x * 256 + tid;
  int v = (i < N_NODES) ? cnt[i] : 0;
  int x = v;
#pragma unroll
  for (int d = 1; d < 64; d <<= 1) {
    int t = __shfl_up(x, d, 64);
    if (lane >= d) x += t;
  }
  if (lane == 63) wpart[wid] = x;
  __syncthreads();
  if (tid == 0) {
    int s = 0;
#pragma unroll
    for (int w = 0; w < 4; ++w) { int t = wpart[w]; wpart[w] = s; s += t; }
    bsum[blockIdx.x] = s;
  }
  __syncthreads();
  if (i < N_NODES) excl[i] = wpart[wid] + x - v;
}

// scan2: boff = exclusive scan of block totals.
__global__ void k_scan2(const int* __restrict__ bsum, int* __restrict__ boff) {
  __shared__ int sd[256];
  int tid = threadIdx.x;
  int v = (tid < NB1) ? bsum[tid] : 0;
  sd[tid] = v;
  __syncthreads();
  for (int d = 1; d < 256; d <<= 1) {
    int t = (tid >= d) ? sd[tid - d] : 0;
    __syncthreads();
    sd[tid] += t;
    __syncthreads();
  }
  if (tid < NB1) boff[tid] = sd[tid] - v;
}

// scatter: global slot = excl[d] + boff[d>>8] + (cnt[d]-- - 1). cnt holds the
// degree from k_hist and is consumed as a descending cursor (neighbor order is
// an arbitrary permutation -> only fp32 reassociation noise downstream).
__global__ void k_scatter(const int* __restrict__ src, const int* __restrict__ dst,
                          const int* __restrict__ excl, const int* __restrict__ boff,
                          int* __restrict__ cnt, int* __restrict__ csr) {
  int i = blockIdx.x * blockDim.x + threadIdx.x;
  if (i < N_EDGES) {
    int d = dst[i];
    int r = atomicAdd(&cnt[d], -1);          // deg .. 1
    csr[excl[d] + boff[d >> 8] + r - 1] = src[i];
  }
}

// ---- aggregation: WAVE per node, 4 edge-slots x 16 feature-lanes, fp8 ------
// lane = es*16 + li: slot es walks edges off(n)+es, +es+4, ... ; lane li
// covers XH features 8li..8li+7 (uint2, 8 B fp8) + eps byte (li&3) of word
// (li>>2). off(n) reconstructed as excl[n] + boff[n>>8] (wave-uniform loads).
__global__ __launch_bounds__(256) void k_agg_ep(
    const uint2* __restrict__ feat2, const unsigned int* __restrict__ epsw,
    const float* __restrict__ geps_p, const int* __restrict__ excl,
    const int* __restrict__ boff, const int* __restrict__ csr,
    uint4* __restrict__ agg4) {
  int wave = (blockIdx.x * blockDim.x + threadIdx.x) >> 6;   // node; grid exact
  int lane = threadIdx.x & 63;
  int li = lane & 15, es = lane >> 4;
  if (wave >= N_NODES) return;
  int n = wave;
  float ge = 1.0f + geps_p[0];
  int wsel = li >> 2, bsh = (li & 3) * 8;

  int off_n = excl[n] + boff[n >> 8];
  int e1 = (n == N_NODES - 1) ? N_EDGES : excl[n + 1] + boff[(n + 1) >> 8];

  // prefetch self row (used after reduction by lanes 0..15)
  uint2 sf = feat2[n * 16 + li];
  unsigned int swd = epsw[n * 4 + wsel];

  float af0 = 0.f, af1 = 0.f, af2 = 0.f, af3 = 0.f;
  float af4 = 0.f, af5 = 0.f, af6 = 0.f, af7 = 0.f;
  unsigned int accLo = 0, accHi = 0;

  int e = off_n + es;
  for (; e + 4 < e1; e += 8) {               // slots stride 4, unroll 2
    int s0 = csr[e], s1 = csr[e + 4];
    uint2 f0 = feat2[s0 * 16 + li];
    uint2 f1 = feat2[s1 * 16 + li];
    unsigned int w0 = epsw[s0 * 4 + wsel];
    unsigned int w1 = epsw[s1 * 4 + wsel];
    f8acc(f0.x, af0, af1, af2, af3);  f8acc(f0.y, af4, af5, af6, af7);
    f8acc(f1.x, af0, af1, af2, af3);  f8acc(f1.y, af4, af5, af6, af7);
    unsigned int B0 = (w0 >> bsh) & 0xFFu;
    unsigned int B1 = (w1 >> bsh) & 0xFFu;
    unsigned int r0 = B0 | (B0 << 8);  r0 |= r0 << 16;
    unsigned int r1 = B1 | (B1 << 8);  r1 |= r1 << 16;
    accLo += spreadLo(r0) + spreadLo(r1);
    accHi += spreadHi(r0) + spreadHi(r1);
  }
  if (e < e1) {
    int s0 = csr[e];
    uint2 f0 = feat2[s0 * 16 + li];
    unsigned int w0 = epsw[s0 * 4 + wsel];
    f8acc(f0.x, af0, af1, af2, af3);  f8acc(f0.y, af4, af5, af6, af7);
    unsigned int B0 = (w0 >> bsh) & 0xFFu;
    unsigned int r0 = B0 | (B0 << 8);  r0 |= r0 << 16;
    accLo += spreadLo(r0);
    accHi += spreadHi(r0);
  }

  // cross-slot reduction (lanes differing in bits 4,5). Packed-byte adds are
  // overflow-safe: per-byte totals <= degree << 255.
#pragma unroll
  for (int d = 16; d < 64; d <<= 1) {
    af0 += __shfl_xor(af0, d, 64);  af1 += __shfl_xor(af1, d, 64);
    af2 += __shfl_xor(af2, d, 64);  af3 += __shfl_xor(af3, d, 64);
    af4 += __shfl_xor(af4, d, 64);  af5 += __shfl_xor(af5, d, 64);
    af6 += __shfl_xor(af6, d, 64);  af7 += __shfl_xor(af7, d, 64);
    accLo += __shfl_xor((int)accLo, d, 64);
    accHi += __shfl_xor((int)accHi, d, 64);
  }

  if (es == 0) {
    // self term (fp8-rounded features, weight ge)
    f32x2 s0 = __builtin_amdgcn_cvt_pk_f32_fp8(sf.x, false);
    f32x2 s1 = __builtin_amdgcn_cvt_pk_f32_fp8(sf.x, true);
    f32x2 s2 = __builtin_amdgcn_cvt_pk_f32_fp8(sf.y, false);
    f32x2 s3 = __builtin_amdgcn_cvt_pk_f32_fp8(sf.y, true);
    af0 += ge * s0.x;  af1 += ge * s0.y;
    af2 += ge * s1.x;  af3 += ge * s1.y;
    af4 += ge * s2.x;  af5 += ge * s2.y;
    af6 += ge * s3.x;  af7 += ge * s3.y;
    unsigned int Bself = (swd >> bsh) & 0xFFu;
    float ev0 = ge * (float)(Bself & 1u)        + (float)(accLo & 0xFFu);
    float ev1 = ge * (float)((Bself >> 1) & 1u) + (float)((accLo >> 8) & 0xFFu);
    float ev2 = ge * (float)((Bself >> 2) & 1u) + (float)((accLo >> 16) & 0xFFu);
    float ev3 = ge * (float)((Bself >> 3) & 1u) + (float)((accLo >> 24) & 0xFFu);
    float ev4 = ge * (float)((Bself >> 4) & 1u) + (float)(accHi & 0xFFu);
    float ev5 = ge * (float)((Bself >> 5) & 1u) + (float)((accHi >> 8) & 0xFFu);
    float ev6 = ge * (float)((Bself >> 6) & 1u) + (float)((accHi >> 16) & 0xFFu);
    float ev7 = ge * (float)((Bself >> 7) & 1u) + (float)((accHi >> 24) & 0xFFu);

    uint4 oXh, oEp;
    oXh.x = pack2(af0, af1); oXh.y = pack2(af2, af3);
    oXh.z = pack2(af4, af5); oXh.w = pack2(af6, af7);
    oEp.x = pack2(ev0, ev1); oEp.y = pack2(ev2, ev3);
    oEp.z = pack2(ev4, ev5); oEp.w = pack2(ev6, ev7);
    agg4[n * 32 + li]      = oXh;   // features 8li..8li+7
    agg4[n * 32 + 16 + li] = oEp;   // eps features 128+8li..+7
  }
}

// ---- MFMA GEMM + bias + ReLU + node-sum -> atomic into sums[512] -----------
__global__ __launch_bounds__(256) void k_gemm(const unsigned short* __restrict__ agg,
    const float* __restrict__ W, const float* __restrict__ b,
    float* __restrict__ sums) {
  int tid = threadIdx.x;
  int lane = tid & 63;
  int w = tid >> 6;          // wave -> n-tiles {2w, 2w+1}
  int col = lane & 15;
  int quad = lane >> 4;

  bf16x8 Bsh[2][4];
  bf16x8 Bep[2];
  float bias[2];
#pragma unroll
  for (int i = 0; i < 2; ++i) {
    int obase = (2 * w + i) * 16;
    bias[i] = b[obase + col];
#pragma unroll
    for (int kb = 0; kb < 4; ++kb) {
      bf16x8 f;
#pragma unroll
      for (int j = 0; j < 8; ++j) {
        int k = kb * 32 + quad * 8 + j;
        int wr = (k < 96) ? k : k + 32;            // h block at W rows 128..159
        f[j] = (short)f2bf(W[wr * D_OUTF + obase + col]);
      }
      Bsh[i][kb] = f;
    }
    bf16x8 g;
#pragma unroll
    for (int j = 0; j < 8; ++j)
      g[j] = (short)f2bf(W[(96 + quad * 8 + j) * D_OUTF + obase + col]);
    Bep[i] = g;
  }

  f32x4 psum[4][2];
#pragma unroll
  for (int s = 0; s < 4; ++s)
#pragma unroll
    for (int i = 0; i < 2; ++i) psum[s][i] = (f32x4){0.f, 0.f, 0.f, 0.f};

  for (int t = blockIdx.x; t < NTILES; t += gridDim.x) {
    const unsigned short* arow = agg + (long)(t * 16 + col) * F_PACK;
    bf16x8 Ash[4];
#pragma unroll
    for (int kb = 0; kb < 4; ++kb)
      Ash[kb] = *(const bf16x8*)(arow + kb * 32 + quad * 8);
    f32x4 csh[2];
    csh[0] = (f32x4){0.f, 0.f, 0.f, 0.f};
    csh[1] = (f32x4){0.f, 0.f, 0.f, 0.f};
#pragma unroll
    for (int kb = 0; kb < 4; ++kb) {
      csh[0] = __builtin_amdgcn_mfma_f32_16x16x32_bf16(Ash[kb], Bsh[0][kb], csh[0], 0, 0, 0);
      csh[1] = __builtin_amdgcn_mfma_f32_16x16x32_bf16(Ash[kb], Bsh[1][kb], csh[1], 0, 0, 0);
    }
#pragma unroll
    for (int s = 0; s < 4; ++s) {
      bf16x8 Aep = *(const bf16x8*)(arow + 128 + s * 32 + quad * 8);
#pragma unroll
      for (int i = 0; i < 2; ++i) {
        f32x4 c = __builtin_amdgcn_mfma_f32_16x16x32_bf16(Aep, Bep[i], csh[i], 0, 0, 0);
#pragma unroll
        for (int r = 0; r < 4; ++r)
          psum[s][i][r] += fmaxf(c[r] + bias[i], 0.f);
      }
    }
  }

#pragma unroll
  for (int s = 0; s < 4; ++s)
#pragma unroll
    for (int i = 0; i < 2; ++i) {
      float v = psum[s][i][0] + psum[s][i][1] + psum[s][i][2] + psum[s][i][3];
      v += __shfl_xor(v, 16, 64);
      v += __shfl_xor(v, 32, 64);
      if (quad == 0)
        atomicAdd(&sums[s * 128 + (2 * w + i) * 16 + col], v);
    }
}

// ---- broadcast output (mean+relu inline) + epsilon passthrough -------------
#define OUT0_F4 6400000L
#define EPS_F4  1600000L
#define INV_N   (1.0f / (float)N_NODES)
__global__ void k_out(const float* __restrict__ sums, const float* __restrict__ eps,
                      float* __restrict__ out) {
  long i = (long)blockIdx.x * blockDim.x + threadIdx.x;
  if (i < OUT0_F4) {
    int o4 = (int)(i & 31);
    long sn = i >> 5;
    int s = (int)(sn / N_NODES);
    float4 sv = ((const float4*)sums)[s * 32 + o4];
    float4 ov;
    ov.x = fmaxf(sv.x * INV_N, 0.f);
    ov.y = fmaxf(sv.y * INV_N, 0.f);
    ov.z = fmaxf(sv.z * INV_N, 0.f);
    ov.w = fmaxf(sv.w * INV_N, 0.f);
    ((float4*)out)[i] = ov;
  } else if (i < OUT0_F4 + EPS_F4) {
    long j = i - OUT0_F4;
    ((float4*)out)[OUT0_F4 + j] = ((const float4*)eps)[j];
  }
}

extern "C" void kernel_launch(void* const* d_in, const int* in_sizes, int n_in,
                              void* d_out, int out_size, void* d_ws, size_t ws_size,
                              hipStream_t stream) {
  const float* X    = (const float*)d_in[0];
  const float* h    = (const float*)d_in[1];
  const float* eps  = (const float*)d_in[2];
  const float* W    = (const float*)d_in[3];
  const float* b    = (const float*)d_in[4];
  const float* geps = (const float*)d_in[5];
  const int*   src  = (const int*)d_in[6];
  const int*   dst  = (const int*)d_in[7];
  float* out = (float*)d_out;

  char* w = (char*)d_ws;
  unsigned int*  featF8 = (unsigned int*)w;  w += (size_t)N_NODES * 32 * 4;   // 6.4 MB
  unsigned int*  epsb   = (unsigned int*)w;  w += (size_t)N_NODES * 4 * 4;    // 0.8 MB
  unsigned int*  agg_u  = (unsigned int*)w;  w += (size_t)N_NODES * 128 * 4;  // 25.6 MB
  int*   excl     = (int*)w;   w += (size_t)(N_NODES + 16) * 4;
  int*   cnt      = (int*)w;   w += (size_t)N_NODES * 4;
  int*   csr      = (int*)w;   w += (size_t)N_EDGES * 4;
  int*   bsum     = (int*)w;   w += 256 * 4;
  int*   boff     = (int*)w;   w += 256 * 4;
  float* sums     = (float*)w; w += 512 * 4;

  int eb = (N_EDGES + 255) / 256;
  k_pack<<<PB_TOT, 256, 0, stream>>>(X, h, eps, featF8, epsb, cnt, sums);
  k_hist<<<eb, 256, 0, stream>>>(dst, cnt);
  k_scan1<<<NB1, 256, 0, stream>>>(cnt, excl, bsum);
  k_scan2<<<1, 256, 0, stream>>>(bsum, boff);
  k_scatter<<<eb, 256, 0, stream>>>(src, dst, excl, boff, cnt, csr);

  k_agg_ep<<<(N_NODES * 64) / 256, 256, 0, stream>>>((const uint2*)featF8, epsb,
                                                     geps, excl, boff, csr,
                                                     (uint4*)agg_u);

  k_gemm<<<GEMM_BLOCKS, 256, 0, stream>>>((const unsigned short*)agg_u, W, b, sums);

  long total_f4 = OUT0_F4 + EPS_F4;
  k_out<<<(int)((total_f4 + 255) / 256), 256, 0, stream>>>(sums, eps, out);
}